// Round 9
// baseline (282.733 us; speedup 1.0000x reference)
//
#include <hip/hip_runtime.h>

#define IH 126
#define IW 126
#define HW 15876      // 126*126
#define OH 124
#define OW 124
#define OHW 15376     // 124*124

// Activations between kernels are HWC: a[(y*IW+x)*64 + c] (r6 win: 256 B runs).

// ---------------------------------------------------------------- conv_in (HWC out)
__global__ __launch_bounds__(256) void conv_in_kernel(
    const float* __restrict__ x, const float* __restrict__ w,
    const float* __restrict__ b, float* __restrict__ y)
{
  int tid = threadIdx.x;
  int oc = tid & 63;
  int w_ = __builtin_amdgcn_readfirstlane(tid >> 6);   // wave 0..3
  int pix = blockIdx.x * 4 + w_;
  if (pix >= HW) return;
  int h  = pix / IW;
  int wc = pix - h * IW;
  const float* wp = w + oc * 27;
  float acc = b[oc];
#pragma unroll
  for (int ci = 0; ci < 3; ci++)
#pragma unroll
    for (int ky = 0; ky < 3; ky++)
#pragma unroll
      for (int kx = 0; kx < 3; kx++)
        acc = fmaf(x[ci * 128 * 128 + (h + ky) * 128 + (wc + kx)],   // uniform
                   wp[ci * 9 + ky * 3 + kx], acc);
  y[pix * 64 + oc] = acc;
}

#define XSW(c, pos) ((c) ^ (((pos) & 7) << 3))
#define WVP4 36       // r6 variant: 32 px padded to 36
#define WVP2 18       // v10 variant: 16 px padded to 18

// ---------------------------------------------------------------- inv variant A (r6, PASSED at 238us)
// 8x4 tile, 512 blocks, LDS 68,864 B -> 2 blocks/CU (4 waves/SIMD).
__global__ __launch_bounds__(512, 4) void inv_kernel(
    const float* __restrict__ x, float* __restrict__ y,
    const float* __restrict__ wr, const float* __restrict__ br,
    const float* __restrict__ gam, const float* __restrict__ bet,
    const float* __restrict__ mu, const float* __restrict__ var,
    const float* __restrict__ wspan, const float* __restrict__ bspan)
{
  __shared__ __align__(16) float xs[140][68];   // 38,080 B
  __shared__ __align__(16) float wvs[196 * WVP4];// 28,224 B
  __shared__ __align__(16) float tss[640];      // 2,560 B; [32 px][20]

  int tid = threadIdx.x;
  int bx = blockIdx.x & 15, by = blockIdx.x >> 4;
  int ox0 = bx * 8, oy0 = by * 4;
  int xh0 = ox0 - 3, yh0 = oy0 - 3;

  // ---- Phase A: stage x halo (14 cols x 10 rows x 64 ch) from HWC, float4
  for (int idx = tid; idx < 140 * 16; idx += 512) {
    int pos = idx >> 4;
    int c4  = (idx & 15) << 2;
    int row = pos / 14;
    int col = pos - row * 14;
    int gy = yh0 + row, gx = xh0 + col;
    float4 v = make_float4(0.f, 0.f, 0.f, 0.f);
    if (gy >= 0 && gy < IH && gx >= 0 && gx < IW)
      v = *(const float4*)&x[(gy * IW + gx) * 64 + c4];
    *(float4*)&xs[pos][XSW(c4, pos)] = v;
  }
  __syncthreads();

  int w_ = __builtin_amdgcn_readfirstlane(tid >> 6);  // wave 0..7
  int ln = tid & 63;
  int p  = ln & 31;                   // pixel 0..31 (upper 32 lanes duplicate)
  int prow = p >> 3, pcol = p & 7;
  int pc = (prow + 3) * 14 + (pcol + 3);

  // ---- Phase B
  {
    int cr0 = 2 * w_;
    const float* wa = wr + cr0 * 64;  // uniform -> s_load
    const float* wb = wa + 64;
    float a0 = 0.f, a1 = 0.f;
    int xsw = (pc & 7) << 3;
#pragma unroll
    for (int ci = 0; ci < 64; ci += 4) {
      int cis = ci ^ xsw;
      float4 xv = *(const float4*)&xs[pc][cis];
      a0 = fmaf(xv.x, wa[cis + 0], a0); a1 = fmaf(xv.x, wb[cis + 0], a1);
      a0 = fmaf(xv.y, wa[cis + 1], a0); a1 = fmaf(xv.y, wb[cis + 1], a1);
      a0 = fmaf(xv.z, wa[cis + 2], a0); a1 = fmaf(xv.z, wb[cis + 2], a1);
      a0 = fmaf(xv.w, wa[cis + 3], a0); a1 = fmaf(xv.w, wb[cis + 3], a1);
    }
    float s0 = gam[cr0]     * rsqrtf(var[cr0]     + 1e-5f);
    float s1 = gam[cr0 + 1] * rsqrtf(var[cr0 + 1] + 1e-5f);
    float t0 = (a0 + br[cr0]     - mu[cr0])     * s0 + bet[cr0];
    float t1 = (a1 + br[cr0 + 1] - mu[cr0 + 1]) * s1 + bet[cr0 + 1];
    if (ln < 32) {
      tss[p * 20 + cr0]     = fmaxf(t0, 0.f);
      tss[p * 20 + cr0 + 1] = fmaxf(t1, 0.f);
    }
  }
  __syncthreads();

  // ---- Phase C
  {
    float tv[16];
#pragma unroll
    for (int i = 0; i < 4; i++) {
      float4 t4 = *(const float4*)&tss[p * 20 + 4 * i];
      tv[4 * i] = t4.x; tv[4 * i + 1] = t4.y;
      tv[4 * i + 2] = t4.z; tv[4 * i + 3] = t4.w;
    }
    for (int j = 0; j < 25; j++) {
      int pair = w_ + 8 * j;           // wave-uniform
      if (pair < 196) {
        const float* wk = wspan + pair * 16;   // uniform -> s_load_dwordx16
        float a = bspan[pair];
#pragma unroll
        for (int i = 0; i < 16; i++) a = fmaf(tv[i], wk[i], a);
        if (ln < 32) wvs[pair * WVP4 + pcol * 4 + prow] = a;
      }
    }
  }
  __syncthreads();

  // ---- Phase D
  float acc0 = 0.f, acc1 = 0.f, acc2 = 0.f, acc3 = 0.f;
  {
    int c = ln;
    int g = ln >> 4;
    float xw[4][7];
#pragma unroll
    for (int r = 0; r < 4; r++)
#pragma unroll
      for (int kx = 0; kx < 7; kx++) {
        int pos = r * 14 + w_ + kx;
        xw[r][kx] = xs[pos][XSW(c, pos)];
      }
#pragma unroll
    for (int ky = 0; ky < 7; ky++) {
      if (ky > 0) {
#pragma unroll
        for (int r = 0; r < 3; r++)
#pragma unroll
          for (int kx = 0; kx < 7; kx++) xw[r][kx] = xw[r + 1][kx];
#pragma unroll
        for (int kx = 0; kx < 7; kx++) {
          int pos = (ky + 3) * 14 + w_ + kx;
          xw[3][kx] = xs[pos][XSW(c, pos)];
        }
      }
#pragma unroll
      for (int kx = 0; kx < 7; kx++) {
        int k = ky * 7 + kx;
        float4 w4 = *(const float4*)&wvs[(g * 49 + k) * WVP4 + w_ * 4];
        acc0 = fmaf(w4.x, xw[0][kx], acc0);
        acc1 = fmaf(w4.y, xw[1][kx], acc1);
        acc2 = fmaf(w4.z, xw[2][kx], acc2);
        acc3 = fmaf(w4.w, xw[3][kx], acc3);
      }
    }
  }

  // ---- direct HWC store (outer ReLU fused)
  {
    int c = ln;
    int gx = ox0 + w_;
    if (gx < IW) {
      int base = (oy0 * IW + gx) * 64 + c;
      y[base]               = fmaxf(acc0, 0.f);
      y[base + 1 * IW * 64] = fmaxf(acc1, 0.f);
      if (oy0 + 2 < IH) y[base + 2 * IW * 64] = fmaxf(acc2, 0.f);
      if (oy0 + 3 < IH) y[base + 3 * IW * 64] = fmaxf(acc3, 0.f);
    }
  }
}

// ---------------------------------------------------------------- inv variant B (v10: 3 blocks/CU)
// 8x2 tile, 1008 blocks, LDS 45,856 B -> 3 blocks/CU = 6 waves/SIMD.
// Within-run A/B against variant A (r5 counters said inv is latency-bound).
__global__ __launch_bounds__(512, 4) void inv_kernel2(
    const float* __restrict__ x, float* __restrict__ y,
    const float* __restrict__ wr, const float* __restrict__ br,
    const float* __restrict__ gam, const float* __restrict__ bet,
    const float* __restrict__ mu, const float* __restrict__ var,
    const float* __restrict__ wspan, const float* __restrict__ bspan)
{
  __shared__ __align__(16) float xs[112][68];   // 30,464 B (14 cols x 8 rows)
  __shared__ __align__(16) float wvs[196 * WVP2];// 14,112 B
  __shared__ __align__(16) float tss[320];      // 1,280 B; [16 px][20]

  int tid = threadIdx.x;
  int bx = blockIdx.x & 15, by = blockIdx.x >> 4;   // bx<16, by<63
  int ox0 = bx * 8, oy0 = by * 2;
  int xh0 = ox0 - 3, yh0 = oy0 - 3;

  // ---- Phase A: stage x halo (14 cols x 8 rows x 64 ch) from HWC, float4
  for (int idx = tid; idx < 112 * 16; idx += 512) {
    int pos = idx >> 4;
    int c4  = (idx & 15) << 2;
    int row = pos / 14;
    int col = pos - row * 14;
    int gy = yh0 + row, gx = xh0 + col;
    float4 v = make_float4(0.f, 0.f, 0.f, 0.f);
    if (gy >= 0 && gy < IH && gx >= 0 && gx < IW)
      v = *(const float4*)&x[(gy * IW + gx) * 64 + c4];
    *(float4*)&xs[pos][XSW(c4, pos)] = v;
  }
  __syncthreads();

  int w_ = __builtin_amdgcn_readfirstlane(tid >> 6);  // wave 0..7
  int ln = tid & 63;
  int p  = ln & 15;                   // pixel 0..15 (upper lanes quadruplicate)
  int prow = p >> 3, pcol = p & 7;    // prow 0..1, pcol 0..7
  int pc = (prow + 3) * 14 + (pcol + 3);

  // ---- Phase B
  {
    int cr0 = 2 * w_;
    const float* wa = wr + cr0 * 64;  // uniform -> s_load
    const float* wb = wa + 64;
    float a0 = 0.f, a1 = 0.f;
    int xsw = (pc & 7) << 3;
#pragma unroll
    for (int ci = 0; ci < 64; ci += 4) {
      int cis = ci ^ xsw;
      float4 xv = *(const float4*)&xs[pc][cis];
      a0 = fmaf(xv.x, wa[cis + 0], a0); a1 = fmaf(xv.x, wb[cis + 0], a1);
      a0 = fmaf(xv.y, wa[cis + 1], a0); a1 = fmaf(xv.y, wb[cis + 1], a1);
      a0 = fmaf(xv.z, wa[cis + 2], a0); a1 = fmaf(xv.z, wb[cis + 2], a1);
      a0 = fmaf(xv.w, wa[cis + 3], a0); a1 = fmaf(xv.w, wb[cis + 3], a1);
    }
    float s0 = gam[cr0]     * rsqrtf(var[cr0]     + 1e-5f);
    float s1 = gam[cr0 + 1] * rsqrtf(var[cr0 + 1] + 1e-5f);
    float t0 = (a0 + br[cr0]     - mu[cr0])     * s0 + bet[cr0];
    float t1 = (a1 + br[cr0 + 1] - mu[cr0 + 1]) * s1 + bet[cr0 + 1];
    if (ln < 16) {
      tss[p * 20 + cr0]     = fmaxf(t0, 0.f);
      tss[p * 20 + cr0 + 1] = fmaxf(t1, 0.f);
    }
  }
  __syncthreads();

  // ---- Phase C
  {
    float tv[16];
#pragma unroll
    for (int i = 0; i < 4; i++) {
      float4 t4 = *(const float4*)&tss[p * 20 + 4 * i];
      tv[4 * i] = t4.x; tv[4 * i + 1] = t4.y;
      tv[4 * i + 2] = t4.z; tv[4 * i + 3] = t4.w;
    }
    for (int j = 0; j < 25; j++) {
      int pair = w_ + 8 * j;           // wave-uniform
      if (pair < 196) {
        const float* wk = wspan + pair * 16;   // uniform -> s_load_dwordx16
        float a = bspan[pair];
#pragma unroll
        for (int i = 0; i < 16; i++) a = fmaf(tv[i], wk[i], a);
        if (ln < 16) wvs[pair * WVP2 + pcol * 2 + prow] = a;
      }
    }
  }
  __syncthreads();

  // ---- Phase D
  float acc0 = 0.f, acc1 = 0.f;
  {
    int c = ln;
    int g = ln >> 4;
    float xw[2][7];
#pragma unroll
    for (int r = 0; r < 2; r++)
#pragma unroll
      for (int kx = 0; kx < 7; kx++) {
        int pos = r * 14 + w_ + kx;
        xw[r][kx] = xs[pos][XSW(c, pos)];
      }
#pragma unroll
    for (int ky = 0; ky < 7; ky++) {
      if (ky > 0) {
#pragma unroll
        for (int kx = 0; kx < 7; kx++) xw[0][kx] = xw[1][kx];
#pragma unroll
        for (int kx = 0; kx < 7; kx++) {
          int pos = (ky + 1) * 14 + w_ + kx;
          xw[1][kx] = xs[pos][XSW(c, pos)];
        }
      }
#pragma unroll
      for (int kx = 0; kx < 7; kx++) {
        int k = ky * 7 + kx;
        float2 w2 = *(const float2*)&wvs[(g * 49 + k) * WVP2 + w_ * 2];
        acc0 = fmaf(w2.x, xw[0][kx], acc0);
        acc1 = fmaf(w2.y, xw[1][kx], acc1);
      }
    }
  }

  // ---- direct HWC store (outer ReLU fused)
  {
    int c = ln;
    int gx = ox0 + w_;
    if (gx < IW) {                     // oy0 <= 124, oy0+1 <= 125: rows in range
      int base = (oy0 * IW + gx) * 64 + c;
      y[base]           = fmaxf(acc0, 0.f);
      y[base + IW * 64] = fmaxf(acc1, 0.f);
    }
  }
}

// ---------------------------------------------------------------- conv_out prep
__global__ __launch_bounds__(256) void transpose_w_kernel(
    const float* __restrict__ w, float* __restrict__ wt)
{
  int i = blockIdx.x * 256 + threadIdx.x;
  if (i >= 128 * 64 * 9) return;
  int oc = i / 576;
  int rem = i - oc * 576;
  int ci = rem / 9;
  int k = rem - ci * 9;
  wt[(k * 64 + ci) * 128 + oc] = w[i];
}

// ---------------------------------------------------------------- conv_out v3 (split by oc_base)
__global__ __launch_bounds__(256, 6) void conv_out_kernel(
    const float* __restrict__ x, const float* __restrict__ wt,
    const float* __restrict__ b, float* __restrict__ y, int oc_base)
{
  __shared__ __align__(16) float xsm[16 * 100 * 4];   // 25,600 B
  int tid = threadIdx.x;
  int bx = blockIdx.x & 15, by = blockIdx.x >> 4;
  int oy0 = by * 8, ox0 = bx * 8;

  for (int u = tid; u < 1600; u += 256) {
    int cq = u / 100;
    int pos = u - cq * 100;
    int row = pos / 10;
    int col = pos - row * 10;
    int gy = oy0 + row, gx = ox0 + col;
    float4 v = make_float4(0.f, 0.f, 0.f, 0.f);
    if (gy < IH && gx < IW)
      v = *(const float4*)&x[(gy * IW + gx) * 64 + cq * 4];
    *(float4*)&xsm[u * 4] = v;
  }
  __syncthreads();

  int ln = tid & 63;
  int px = ln & 7, py = ln >> 3;
  int wv_ = __builtin_amdgcn_readfirstlane(tid >> 6);   // wave 0..3
  int oc8 = oc_base + blockIdx.y * 32 + wv_ * 8;

  float acc[8];
#pragma unroll
  for (int j = 0; j < 8; j++) acc[j] = b[oc8 + j];

#pragma unroll
  for (int ky = 0; ky < 3; ky++) {
#pragma unroll
    for (int kx = 0; kx < 3; kx++) {
      int k = ky * 3 + kx;
      int pidx = (py + ky) * 10 + px + kx;
      const float* wp = wt + k * 64 * 128 + oc8;   // uniform -> s_loads
#pragma unroll 4
      for (int cq = 0; cq < 16; cq++) {
        float4 xv = *(const float4*)&xsm[(cq * 100 + pidx) * 4];
        const float* wq = wp + cq * 4 * 128;
#pragma unroll
        for (int j = 0; j < 8; j++) {
          acc[j] = fmaf(xv.x, wq[0 * 128 + j], acc[j]);
          acc[j] = fmaf(xv.y, wq[1 * 128 + j], acc[j]);
          acc[j] = fmaf(xv.z, wq[2 * 128 + j], acc[j]);
          acc[j] = fmaf(xv.w, wq[3 * 128 + j], acc[j]);
        }
      }
    }
  }

  int oy = oy0 + py, ox = ox0 + px;
  if (oy < OH && ox < OW) {
#pragma unroll
    for (int j = 0; j < 8; j++)
      y[(oc8 + j) * OHW + oy * OW + ox] = acc[j];
  }
}

// ---------------------------------------------------------------- launch
extern "C" void kernel_launch(void* const* d_in, const int* in_sizes, int n_in,
                              void* d_out, int out_size, void* d_ws, size_t ws_size,
                              hipStream_t stream)
{
  const float* input = (const float*)d_in[0];
  const float* ciw   = (const float*)d_in[1];
  const float* cib   = (const float*)d_in[2];
  const float* wred  = (const float*)d_in[3];
  const float* bred  = (const float*)d_in[4];
  const float* gam   = (const float*)d_in[5];
  const float* bet   = (const float*)d_in[6];
  const float* mu    = (const float*)d_in[7];
  const float* var   = (const float*)d_in[8];
  const float* wspan = (const float*)d_in[9];
  const float* bspan = (const float*)d_in[10];
  const float* cow   = (const float*)d_in[11];
  const float* cob   = (const float*)d_in[12];
  float* out = (float*)d_out;

  float* bufA = (float*)d_ws;                 // HWC: 15876*64 = 1,016,064 floats
  float* bufB = bufA + (1 << 20);             // @ 4 MiB
  float* wt   = bufA + (1 << 21);             // @ 8 MiB, 73,728 floats

  transpose_w_kernel<<<288, 256, 0, stream>>>(cow, wt);
  conv_in_kernel<<<3969, 256, 0, stream>>>(input, ciw, cib, bufA);

  float* cur = bufA; float* nxt = bufB;
  for (int i = 0; i < 6; i++) {
    if (i & 1) {
      // variant A: r6-proven 8x4 tile, 2 blocks/CU
      inv_kernel<<<512, 512, 0, stream>>>(cur, nxt,
          wred + i * 16 * 64, bred + i * 16, gam + i * 16, bet + i * 16,
          mu + i * 16, var + i * 16, wspan + i * 196 * 16, bspan + i * 196);
    } else {
      // variant B: 8x2 tile, 3 blocks/CU (6 waves/SIMD) — concurrency probe
      inv_kernel2<<<1008, 512, 0, stream>>>(cur, nxt,
          wred + i * 16 * 64, bred + i * 16, gam + i * 16, bet + i * 16,
          mu + i * 16, var + i * 16, wspan + i * 196 * 16, bspan + i * 196);
    }
    float* t = cur; cur = nxt; nxt = t;
  }
  conv_out_kernel<<<dim3(256, 2), 256, 0, stream>>>(cur, wt, cob, out, 0);
  conv_out_kernel<<<dim3(256, 2), 256, 0, stream>>>(cur, wt, cob, out, 64);
}

// Round 10
// 250.236 us; speedup vs baseline: 1.1299x; 1.1299x over previous
//
#include <hip/hip_runtime.h>

#define IH 126
#define IW 126
#define HW 15876      // 126*126
#define OH 124
#define OW 124
#define OHW 15376     // 124*124

// Activations between kernels are HWC: a[(y*IW+x)*64 + c] (r6 win: 256 B runs).

// ---------------------------------------------------------------- conv_in (HWC out)
__global__ __launch_bounds__(256) void conv_in_kernel(
    const float* __restrict__ x, const float* __restrict__ w,
    const float* __restrict__ b, float* __restrict__ y)
{
  int tid = threadIdx.x;
  int oc = tid & 63;
  int w_ = __builtin_amdgcn_readfirstlane(tid >> 6);   // wave 0..3
  int pix = blockIdx.x * 4 + w_;
  if (pix >= HW) return;
  int h  = pix / IW;
  int wc = pix - h * IW;
  const float* wp = w + oc * 27;
  float acc = b[oc];
#pragma unroll
  for (int ci = 0; ci < 3; ci++)
#pragma unroll
    for (int ky = 0; ky < 3; ky++)
#pragma unroll
      for (int kx = 0; kx < 3; kx++)
        acc = fmaf(x[ci * 128 * 128 + (h + ky) * 128 + (wc + kx)],   // uniform
                   wp[ci * 9 + ky * 3 + kx], acc);
  y[pix * 64 + oc] = acc;
}

#define XSW(c, pos) ((c) ^ (((pos) & 7) << 3))
#define WVP4 36

// ---------------------------------------------------------------- involution v11
// r6-proven 8x4 structure + de-serialization:
//  - wr staged in LDS (4 KB): phase B all-LDS (r4's swizzle had turned the
//    uniform weight s_loads into global gathers; LDS-permuted read is <=2-way
//    bank aliased = free).
//  - phase C: results accumulate in regs, ds_writes AFTER the s_load loop
//    (per-iteration ds_write forced lgkmcnt(0) drains between s_load batches).
// LDS 72,960 B -> 2 blocks/CU.
__global__ __launch_bounds__(512, 4) void inv_kernel(
    const float* __restrict__ x, float* __restrict__ y,
    const float* __restrict__ wr, const float* __restrict__ br,
    const float* __restrict__ gam, const float* __restrict__ bet,
    const float* __restrict__ mu, const float* __restrict__ var,
    const float* __restrict__ wspan, const float* __restrict__ bspan)
{
  __shared__ __align__(16) float xs[140][68];    // 38,080 B
  __shared__ __align__(16) float wvs[196 * WVP4];// 28,224 B
  __shared__ __align__(16) float tss[640];       // 2,560 B; [32 px][20]
  __shared__ __align__(16) float wrs[1024];      // 4,096 B; staged Wr [16][64]

  int tid = threadIdx.x;
  int bx = blockIdx.x & 15, by = blockIdx.x >> 4;
  int ox0 = bx * 8, oy0 = by * 4;
  int xh0 = ox0 - 3, yh0 = oy0 - 3;

  // ---- Phase A: stage x halo (14 x 10 x 64 ch) from HWC + Wr into LDS
  for (int idx = tid; idx < 140 * 16; idx += 512) {
    int pos = idx >> 4;
    int c4  = (idx & 15) << 2;
    int row = pos / 14;
    int col = pos - row * 14;
    int gy = yh0 + row, gx = xh0 + col;
    float4 v = make_float4(0.f, 0.f, 0.f, 0.f);
    if (gy >= 0 && gy < IH && gx >= 0 && gx < IW)
      v = *(const float4*)&x[(gy * IW + gx) * 64 + c4];
    *(float4*)&xs[pos][XSW(c4, pos)] = v;
  }
  for (int j = tid; j < 1024; j += 512) wrs[j] = wr[j];
  __syncthreads();

  int w_ = __builtin_amdgcn_readfirstlane(tid >> 6);  // wave 0..7
  int ln = tid & 63;
  int p  = ln & 31;                   // pixel 0..31 (upper 32 lanes duplicate)
  int prow = p >> 3, pcol = p & 7;
  int pc = (prow + 3) * 14 + (pcol + 3);

  // ---- Phase B: t = ReLU(BN(Wr.x)); all operands from LDS (no SMEM in loop)
  {
    int cr0 = 2 * w_;
    const float* wa = &wrs[cr0 * 64];
    const float* wb = wa + 64;
    float a0 = 0.f, a1 = 0.f;
    int xsw = (pc & 7) << 3;
#pragma unroll
    for (int ci = 0; ci < 64; ci += 4) {
      int cis = ci ^ xsw;             // quad-aligned: b128-able; <=2-way banks
      float4 xv = *(const float4*)&xs[pc][cis];
      float4 av = *(const float4*)&wa[cis];
      float4 bv = *(const float4*)&wb[cis];
      a0 = fmaf(xv.x, av.x, a0); a1 = fmaf(xv.x, bv.x, a1);
      a0 = fmaf(xv.y, av.y, a0); a1 = fmaf(xv.y, bv.y, a1);
      a0 = fmaf(xv.z, av.z, a0); a1 = fmaf(xv.z, bv.z, a1);
      a0 = fmaf(xv.w, av.w, a0); a1 = fmaf(xv.w, bv.w, a1);
    }
    float s0 = gam[cr0]     * rsqrtf(var[cr0]     + 1e-5f);
    float s1 = gam[cr0 + 1] * rsqrtf(var[cr0 + 1] + 1e-5f);
    float t0 = (a0 + br[cr0]     - mu[cr0])     * s0 + bet[cr0];
    float t1 = (a1 + br[cr0 + 1] - mu[cr0 + 1]) * s1 + bet[cr0 + 1];
    if (ln < 32) {
      tss[p * 20 + cr0]     = fmaxf(t0, 0.f);
      tss[p * 20 + cr0 + 1] = fmaxf(t1, 0.f);
    }
  }
  __syncthreads();

  // ---- Phase C: span. s_load batches pipeline freely (no ds ops in loop);
  //      all wvs writes deferred to a single pass at the end.
  {
    float tv[16];
#pragma unroll
    for (int i = 0; i < 4; i++) {
      float4 t4 = *(const float4*)&tss[p * 20 + 4 * i];
      tv[4 * i] = t4.x; tv[4 * i + 1] = t4.y;
      tv[4 * i + 2] = t4.z; tv[4 * i + 3] = t4.w;
    }
    float wv[25];
#pragma unroll
    for (int j = 0; j < 25; j++) {
      int pair = w_ + 8 * j;           // wave-uniform
      float a = 0.f;
      if (pair < 196) {
        const float* wk = wspan + pair * 16;   // uniform -> s_load_dwordx16
        a = bspan[pair];
#pragma unroll
        for (int i = 0; i < 16; i++) a = fmaf(tv[i], wk[i], a);
      }
      wv[j] = a;
    }
    if (ln < 32) {
#pragma unroll
      for (int j = 0; j < 25; j++) {
        int pair = w_ + 8 * j;
        if (pair < 196) wvs[pair * WVP4 + pcol * 4 + prow] = wv[j];
      }
    }
  }
  __syncthreads();

  // ---- Phase D: einsum. wave = output column w_, lane = channel. (all-LDS)
  float acc0 = 0.f, acc1 = 0.f, acc2 = 0.f, acc3 = 0.f;
  {
    int c = ln;
    int g = ln >> 4;
    float xw[4][7];
#pragma unroll
    for (int r = 0; r < 4; r++)
#pragma unroll
      for (int kx = 0; kx < 7; kx++) {
        int pos = r * 14 + w_ + kx;
        xw[r][kx] = xs[pos][XSW(c, pos)];
      }
#pragma unroll
    for (int ky = 0; ky < 7; ky++) {
      if (ky > 0) {
#pragma unroll
        for (int r = 0; r < 3; r++)
#pragma unroll
          for (int kx = 0; kx < 7; kx++) xw[r][kx] = xw[r + 1][kx];
#pragma unroll
        for (int kx = 0; kx < 7; kx++) {
          int pos = (ky + 3) * 14 + w_ + kx;
          xw[3][kx] = xs[pos][XSW(c, pos)];
        }
      }
#pragma unroll
      for (int kx = 0; kx < 7; kx++) {
        int k = ky * 7 + kx;
        float4 w4 = *(const float4*)&wvs[(g * 49 + k) * WVP4 + w_ * 4];
        acc0 = fmaf(w4.x, xw[0][kx], acc0);
        acc1 = fmaf(w4.y, xw[1][kx], acc1);
        acc2 = fmaf(w4.z, xw[2][kx], acc2);
        acc3 = fmaf(w4.w, xw[3][kx], acc3);
      }
    }
  }

  // ---- direct HWC store (outer ReLU fused)
  {
    int c = ln;
    int gx = ox0 + w_;
    if (gx < IW) {
      int base = (oy0 * IW + gx) * 64 + c;
      y[base]               = fmaxf(acc0, 0.f);
      y[base + 1 * IW * 64] = fmaxf(acc1, 0.f);
      if (oy0 + 2 < IH) y[base + 2 * IW * 64] = fmaxf(acc2, 0.f);
      if (oy0 + 3 < IH) y[base + 3 * IW * 64] = fmaxf(acc3, 0.f);
    }
  }
}

// ---------------------------------------------------------------- conv_out prep
__global__ __launch_bounds__(256) void transpose_w_kernel(
    const float* __restrict__ w, float* __restrict__ wt)
{
  int i = blockIdx.x * 256 + threadIdx.x;
  if (i >= 128 * 64 * 9) return;
  int oc = i / 576;
  int rem = i - oc * 576;
  int ci = rem / 9;
  int k = rem - ci * 9;
  wt[(k * 64 + ci) * 128 + oc] = w[i];
}

// ---------------------------------------------------------------- conv_out v6
// r9 diagnosis: time == per-block path, dominated by per-iteration
// s_load -> s_waitcnt lgkmcnt(0) (SMEM+DS share lgkmcnt; SMEM out-of-order
// forces full drains -> no pipelining). Fix: per-tap weight slab staged in
// LDS (8.2 KB), inner loop all-LDS broadcast reads. Wave mapping identical
// to proven v3. LDS 33.8 KB -> 4 blocks/CU, grid (256,4).
__global__ __launch_bounds__(256, 4) void conv_out_kernel(
    const float* __restrict__ x, const float* __restrict__ wt,
    const float* __restrict__ b, float* __restrict__ y)
{
  __shared__ __align__(16) float xsm[16 * 100 * 4];   // 25,600 B
  __shared__ __align__(16) float wsm[2048];           // 8,192 B: [64 ci][32 oc]
  int tid = threadIdx.x;
  int bx = blockIdx.x & 15, by = blockIdx.x >> 4;
  int oy0 = by * 8, ox0 = bx * 8;
  int ocb = blockIdx.y * 32;

  for (int u = tid; u < 1600; u += 256) {
    int cq = u / 100;
    int pos = u - cq * 100;
    int row = pos / 10;
    int col = pos - row * 10;
    int gy = oy0 + row, gx = ox0 + col;
    float4 v = make_float4(0.f, 0.f, 0.f, 0.f);
    if (gy < IH && gx < IW)
      v = *(const float4*)&x[(gy * IW + gx) * 64 + cq * 4];
    *(float4*)&xsm[u * 4] = v;
  }

  int ln = tid & 63;
  int px = ln & 7, py = ln >> 3;
  int wv_ = __builtin_amdgcn_readfirstlane(tid >> 6);   // wave 0..3
  int oc8 = ocb + wv_ * 8;

  float acc[8];
#pragma unroll
  for (int j = 0; j < 8; j++) acc[j] = b[oc8 + j];

  for (int k = 0; k < 9; k++) {
    if (k) __syncthreads();            // prev chunk's reads done
    // stage tap k's [64 ci][32 oc] slab: 512 float4, 2 per thread, coalesced
    for (int u = tid; u < 512; u += 256) {
      int ci = u >> 3;
      int o4 = (u & 7) << 2;
      *(float4*)&wsm[ci * 32 + o4] =
          *(const float4*)&wt[(k * 64 + ci) * 128 + ocb + o4];
    }
    __syncthreads();                   // (also covers xsm on k==0)

    int ky = k / 3, kx = k - ky * 3;
    int pidx = (py + ky) * 10 + px + kx;
#pragma unroll 4
    for (int cq = 0; cq < 16; cq++) {
      float4 xv = *(const float4*)&xsm[(cq * 100 + pidx) * 4];
      const float* wq = &wsm[cq * 4 * 32 + wv_ * 8];   // uniform -> broadcast
#pragma unroll
      for (int j = 0; j < 8; j++) {
        acc[j] = fmaf(xv.x, wq[0 * 32 + j], acc[j]);
        acc[j] = fmaf(xv.y, wq[1 * 32 + j], acc[j]);
        acc[j] = fmaf(xv.z, wq[2 * 32 + j], acc[j]);
        acc[j] = fmaf(xv.w, wq[3 * 32 + j], acc[j]);
      }
    }
  }

  int oy = oy0 + py, ox = ox0 + px;
  if (oy < OH && ox < OW) {
#pragma unroll
    for (int j = 0; j < 8; j++)
      y[(oc8 + j) * OHW + oy * OW + ox] = acc[j];
  }
}

// ---------------------------------------------------------------- launch
extern "C" void kernel_launch(void* const* d_in, const int* in_sizes, int n_in,
                              void* d_out, int out_size, void* d_ws, size_t ws_size,
                              hipStream_t stream)
{
  const float* input = (const float*)d_in[0];
  const float* ciw   = (const float*)d_in[1];
  const float* cib   = (const float*)d_in[2];
  const float* wred  = (const float*)d_in[3];
  const float* bred  = (const float*)d_in[4];
  const float* gam   = (const float*)d_in[5];
  const float* bet   = (const float*)d_in[6];
  const float* mu    = (const float*)d_in[7];
  const float* var   = (const float*)d_in[8];
  const float* wspan = (const float*)d_in[9];
  const float* bspan = (const float*)d_in[10];
  const float* cow   = (const float*)d_in[11];
  const float* cob   = (const float*)d_in[12];
  float* out = (float*)d_out;

  float* bufA = (float*)d_ws;                 // HWC: 15876*64 = 1,016,064 floats
  float* bufB = bufA + (1 << 20);             // @ 4 MiB
  float* wt   = bufA + (1 << 21);             // @ 8 MiB, 73,728 floats

  transpose_w_kernel<<<288, 256, 0, stream>>>(cow, wt);
  conv_in_kernel<<<3969, 256, 0, stream>>>(input, ciw, cib, bufA);

  float* cur = bufA; float* nxt = bufB;
  for (int i = 0; i < 6; i++) {
    inv_kernel<<<512, 512, 0, stream>>>(cur, nxt,
        wred + i * 16 * 64, bred + i * 16, gam + i * 16, bet + i * 16,
        mu + i * 16, var + i * 16, wspan + i * 196 * 16, bspan + i * 196);
    float* t = cur; cur = nxt; nxt = t;
  }
  conv_out_kernel<<<dim3(256, 4), 256, 0, stream>>>(cur, wt, cob, out);
}